// Round 5
// baseline (109.682 us; speedup 1.0000x reference)
//
#include <hip/hip_runtime.h>
#include <stdint.h>

// Resubmission of Round-4 kernel: composed entirely of harness-verified
// components (k_prep/k_scatter from R0 @100.5us absmax 0.0; k_mine+distributed
// loss tail from R2 @109us absmax 0.0). R3/R4 bench failures were container-
// level (R3's spin-barrier kernel likely wedged the node; R4 collateral).

#define N 8192
#define D 256
#define NSUBJ 16
#define PADS 768                 // padded slot per subject (mean 512, +11 sigma safe)
#define GN (NSUBJ * PADS)        // 12288 gathered rows
#define MARGIN 1.0f

typedef __attribute__((ext_vector_type(8))) short short8;   // 8 bf16 = 4 VGPRs (MFMA A/B frag)
typedef __attribute__((ext_vector_type(4))) float f32x4;    // MFMA C/D frag
typedef __attribute__((ext_vector_type(4))) unsigned short us4;
typedef unsigned long long u64;

__device__ __forceinline__ unsigned short f2bf(float x) {
    unsigned u = __float_as_uint(x);
    u += 0x7fffu + ((u >> 16) & 1u);
    return (unsigned short)(u >> 16);
}

// ---------------- ws layout ----------------
// ushort gH[GN*D]; u64 posP[GN]; u64 negP[GN]; int gIdx[GN]; int gLab[GN];
// float gSq[GN]; int writePtr[16]; int doneS[16]; int doneG; float partialS[16];
// float partialC[16]; int pos[N]

// R0-proven: init (posP/negP/gIdx/gLab all slots) + within-subject rank scan
// (1 block/subject). Also zeroes doneS/doneG for the k_mine tail cascade.
__global__ void k_prep(const int* __restrict__ sbjv, int* __restrict__ pos,
                       int* __restrict__ writePtr, int* __restrict__ gIdx,
                       int* __restrict__ gLab, u64* __restrict__ posP,
                       u64* __restrict__ negP, int* __restrict__ doneS,
                       int* __restrict__ doneG) {
    int s = blockIdx.x;                 // 0..15
    int tid = threadIdx.x;              // 256
    int lane = tid & 63, w = tid >> 6;

    #pragma unroll
    for (int it = 0; it < 3; ++it) {
        int slot = s * PADS + it * 256 + tid;
        gIdx[slot] = -1;
        gLab[slot] = -2;
        posP[slot] = 0ull;
        negP[slot] = ~0ull;
    }
    if (tid == 0) {
        doneS[s] = 0;
        if (s == 0) *doneG = 0;
    }

    __shared__ int wsum[4];
    __shared__ int carry;
    if (tid == 0) carry = s * PADS;
    __syncthreads();

    for (int iter = 0; iter < 8; ++iter) {          // 1024 rows per iter, int4/thread
        int r0 = iter * 1024 + tid * 4;
        int4 sv = *(const int4*)(sbjv + r0);
        int m0 = (sv.x == s), m1 = (sv.y == s), m2 = (sv.z == s), m3 = (sv.w == s);
        int cnt = m0 + m1 + m2 + m3;
        int x = cnt;                                 // wave inclusive scan
        #pragma unroll
        for (int o = 1; o < 64; o <<= 1) {
            int y = __shfl_up(x, o, 64);
            if (lane >= o) x += y;
        }
        if (lane == 63) wsum[w] = x;
        __syncthreads();                             // A: wsum + carry visible
        int b = carry + (x - cnt);
        #pragma unroll
        for (int ww = 0; ww < 4; ++ww) if (ww < w) b += wsum[ww];
        if (m0) pos[r0 + 0] = b++;
        if (m1) pos[r0 + 1] = b++;
        if (m2) pos[r0 + 2] = b++;
        if (m3) pos[r0 + 3] = b++;
        __syncthreads();                             // B: all reads of carry done
        if (tid == 0) carry += wsum[0] + wsum[1] + wsum[2] + wsum[3];
    }
    __syncthreads();
    if (tid == 0) writePtr[s] = carry;               // == s*PADS + count(s)
}

// R0-proven: gather rows by subject into precomputed slots; fp32 -> bf16;
// fold in sq-norm. posP/negP already initialized by k_prep.
__global__ void k_scatter(const float* __restrict__ emb, const int* __restrict__ labels,
                          const int* __restrict__ sbjv, const int* __restrict__ pos,
                          unsigned short* __restrict__ gH, int* __restrict__ gIdx,
                          int* __restrict__ gLab, float* __restrict__ gSq) {
    int wave = threadIdx.x >> 6;
    int lane = threadIdx.x & 63;
    int row = blockIdx.x * 4 + wave;
    const float4* e4 = (const float4*)(emb + (size_t)row * D);
    float4 v = e4[lane];
    float s = v.x * v.x + v.y * v.y + v.z * v.z + v.w * v.w;
    #pragma unroll
    for (int o = 32; o; o >>= 1) s += __shfl_xor(s, o, 64);
    int p = pos[row];                    // wave-uniform load, no atomics
    us4 h;
    h.x = f2bf(v.x); h.y = f2bf(v.y); h.z = f2bf(v.z); h.w = f2bf(v.w);
    *(us4*)(gH + (size_t)p * D + lane * 4) = h;
    if (lane == 0) { gIdx[p] = row; gLab[p] = labels[row]; gSq[p] = s; }
}

// mining body for one 64x64 tile (one wave). Identical math to the proven
// R0/R2 k_mine (bit-identical packed keys).
__device__ __forceinline__ void mine_tile(
        int s, int rowt, int ctile, int lane,
        const unsigned short* __restrict__ gH, const int* __restrict__ gIdx,
        const int* __restrict__ gLab, const float* __restrict__ gSq,
        const int* __restrict__ writePtr,
        u64* __restrict__ posP, u64* __restrict__ negP) {
    int quad = lane >> 4, l15 = lane & 15;
    int base = s * PADS;
    int cntS = writePtr[s] - base;
    if (rowt * 64 >= cntS || ctile * 64 >= cntS) return;   // wave-uniform exit
    int i0 = base + rowt * 64;
    int j0 = base + ctile * 64;

    int labc[4], idxc[4];
    float sqc[4];
    #pragma unroll
    for (int nt = 0; nt < 4; ++nt) {
        int cidx = j0 + nt * 16 + l15;
        labc[nt] = gLab[cidx]; idxc[nt] = gIdx[cidx]; sqc[nt] = gSq[cidx];
    }
    int labr[4][4], idxr[4][4];
    float sqr[4][4];
    #pragma unroll
    for (int mt = 0; mt < 4; ++mt)
        #pragma unroll
        for (int rg = 0; rg < 4; ++rg) {
            int r = i0 + mt * 16 + quad * 4 + rg;
            labr[mt][rg] = gLab[r]; idxr[mt][rg] = gIdx[r]; sqr[mt][rg] = gSq[r];
        }

    f32x4 acc[4][4];
    #pragma unroll
    for (int mt = 0; mt < 4; ++mt)
        #pragma unroll
        for (int nt = 0; nt < 4; ++nt) {
            f32x4 z = {0.f, 0.f, 0.f, 0.f};
            acc[mt][nt] = z;
        }

    #pragma unroll 2
    for (int kb = 0; kb < 8; ++kb) {
        int koff = kb * 32 + quad * 8;
        short8 a[4], b[4];
        #pragma unroll
        for (int mt = 0; mt < 4; ++mt)
            a[mt] = *(const short8*)(gH + (size_t)(i0 + mt * 16 + l15) * D + koff);
        #pragma unroll
        for (int nt = 0; nt < 4; ++nt)
            b[nt] = *(const short8*)(gH + (size_t)(j0 + nt * 16 + l15) * D + koff);
        #pragma unroll
        for (int mt = 0; mt < 4; ++mt)
            #pragma unroll
            for (int nt = 0; nt < 4; ++nt)
                acc[mt][nt] = __builtin_amdgcn_mfma_f32_16x16x32_bf16(
                    a[mt], b[nt], acc[mt][nt], 0, 0, 0);
    }

    // ---- mining epilogue: C layout col = lane&15, row = quad*4 + reg ----
    #pragma unroll
    for (int mt = 0; mt < 4; ++mt) {
        u64 bp[4], bn[4];
        #pragma unroll
        for (int rg = 0; rg < 4; ++rg) { bp[rg] = 0ull; bn[rg] = ~0ull; }
        #pragma unroll
        for (int nt = 0; nt < 4; ++nt) {
            int lc = labc[nt], ic = idxc[nt];
            float sc = sqc[nt];
            f32x4 v = acc[mt][nt];
            #pragma unroll
            for (int rg = 0; rg < 4; ++rg) {
                float d2 = fmaxf(sqr[mt][rg] + sc - 2.0f * v[rg], 0.0f);
                u64 db = ((u64)__float_as_uint(d2)) << 32;
                if (lc == labr[mt][rg] && ic != idxr[mt][rg] && ic >= 0) {
                    u64 pk = db | (u64)(unsigned)(~(unsigned)ic);
                    if (pk > bp[rg]) bp[rg] = pk;
                }
                if (lc != labr[mt][rg] && ic >= 0) {
                    u64 nk = db | (u64)(unsigned)ic;
                    if (nk < bn[rg]) bn[rg] = nk;
                }
            }
        }
        #pragma unroll
        for (int o = 1; o < 16; o <<= 1) {
            #pragma unroll
            for (int rg = 0; rg < 4; ++rg) {
                u64 pp = __shfl_xor(bp[rg], o, 64);
                if (pp > bp[rg]) bp[rg] = pp;
                u64 qq = __shfl_xor(bn[rg], o, 64);
                if (qq < bn[rg]) bn[rg] = qq;
            }
        }
        if (l15 == 0) {
            #pragma unroll
            for (int rg = 0; rg < 4; ++rg) {
                int r = i0 + mt * 16 + quad * 4 + rg;
                if (bp[rg]) atomicMax(&posP[r], bp[rg]);
                if (bn[rg] != ~0ull) atomicMin(&negP[r], bn[rg]);
            }
        }
    }
}

// R2-proven: mining + distributed loss tail (per-subject finisher cascade).
// No cooperative launch, no grid.sync, no spin barrier.
__global__ __launch_bounds__(256) void k_mine(
        const unsigned short* __restrict__ gH, const int* __restrict__ gIdx,
        const int* __restrict__ gLab, const float* __restrict__ gSq,
        const int* __restrict__ writePtr,
        u64* __restrict__ posP, u64* __restrict__ negP,
        int* __restrict__ doneS, int* __restrict__ doneG,
        float* __restrict__ partialS, float* __restrict__ partialC,
        float* __restrict__ out) {
    int blk = blockIdx.x;
    int s   = blk / 36;
    int rem = blk % 36;
    int rowt = rem / 3, cgp = rem % 3;
    int tid  = threadIdx.x;
    int lane = tid & 63, w = tid >> 6;
    int ctile = cgp * 4 + w;

    mine_tile(s, rowt, ctile, lane, gH, gIdx, gLab, gSq, writePtr, posP, negP);

    // ---- per-subject completion ----
    __syncthreads();
    __shared__ int role;
    if (tid == 0) {
        __threadfence();                        // release this block's atomics
        role = (atomicAdd(&doneS[s], 1) == 35); // last of 36 subject-s blocks
    }
    __syncthreads();
    if (!role) return;

    // ---- subject-s loss partial (deterministic grouping) ----
    __threadfence();
    int base = s * PADS;
    int cntS = writePtr[s] - base;
    float S = 0.f, C = 0.f;
    #pragma unroll
    for (int k = 0; k < 3; ++k) {
        int local = tid + 256 * k;
        if (local < cntS) {
            u64 p  = __hip_atomic_load(&posP[base + local], __ATOMIC_RELAXED,
                                       __HIP_MEMORY_SCOPE_AGENT);
            u64 nn = __hip_atomic_load(&negP[base + local], __ATOMIC_RELAXED,
                                       __HIP_MEMORY_SCOPE_AGENT);
            if (p != 0ull && nn != ~0ull) {
                float dp = sqrtf(__uint_as_float((unsigned)(p >> 32)));
                float dn = sqrtf(__uint_as_float((unsigned)(nn >> 32)));
                S += fmaxf(dp - dn + MARGIN, 0.0f);
                C += 1.0f;
            }
        }
    }
    #pragma unroll
    for (int o = 32; o; o >>= 1) {
        S += __shfl_xor(S, o, 64);
        C += __shfl_xor(C, o, 64);
    }
    __shared__ float ssS[4], ssC[4];
    if (lane == 0) { ssS[w] = S; ssC[w] = C; }
    __syncthreads();
    if (tid == 0) {
        float PS = ssS[0] + ssS[1] + ssS[2] + ssS[3];
        float PC = ssC[0] + ssC[1] + ssC[2] + ssC[3];
        __hip_atomic_store(&partialS[s], PS, __ATOMIC_RELAXED, __HIP_MEMORY_SCOPE_AGENT);
        __hip_atomic_store(&partialC[s], PC, __ATOMIC_RELAXED, __HIP_MEMORY_SCOPE_AGENT);
        __threadfence();
        if (atomicAdd(doneG, 1) == 15) {        // last subject finisher
            __threadfence();
            float TS = 0.f, TC = 0.f;
            #pragma unroll
            for (int s2 = 0; s2 < NSUBJ; ++s2) {
                TS += __hip_atomic_load(&partialS[s2], __ATOMIC_RELAXED,
                                        __HIP_MEMORY_SCOPE_AGENT);
                TC += __hip_atomic_load(&partialC[s2], __ATOMIC_RELAXED,
                                        __HIP_MEMORY_SCOPE_AGENT);
            }
            out[0] = TS / (TC < 1.0f ? 1.0f : TC);
        }
    }
}

extern "C" void kernel_launch(void* const* d_in, const int* in_sizes, int n_in,
                              void* d_out, int out_size, void* d_ws, size_t ws_size,
                              hipStream_t stream) {
    const float* emb  = (const float*)d_in[0];
    const int* labels = (const int*)d_in[1];
    const int* sbjv   = (const int*)d_in[2];
    float* out = (float*)d_out;

    char* ws = (char*)d_ws;
    unsigned short* gH = (unsigned short*)ws;                 // GN*D*2 = 6291456 B
    u64* posP     = (u64*)(ws + 6291456);                     // GN*8 = 98304
    u64* negP     = (u64*)(ws + 6389760);                     // GN*8 = 98304
    int* gIdx     = (int*)(ws + 6488064);                     // GN*4 = 49152
    int* gLab     = (int*)(ws + 6537216);                     // GN*4
    float* gSq    = (float*)(ws + 6586368);                   // GN*4
    int* writePtr = (int*)(ws + 6635520);                     // 64 B
    int* doneS    = (int*)(ws + 6635584);                     // 64 B
    int* doneG    = (int*)(ws + 6635648);                     // 64 B
    float* partialS = (float*)(ws + 6635712);                 // 64 B
    float* partialC = (float*)(ws + 6635776);                 // 64 B
    int* pos      = (int*)(ws + 6635840);                     // N*4 = 32768

    k_prep<<<NSUBJ, 256, 0, stream>>>(sbjv, pos, writePtr, gIdx, gLab, posP,
                                      negP, doneS, doneG);
    k_scatter<<<N / 4, 256, 0, stream>>>(emb, labels, sbjv, pos, gH, gIdx, gLab, gSq);
    k_mine<<<NSUBJ * 12 * 3, 256, 0, stream>>>(gH, gIdx, gLab, gSq, writePtr,
                                               posP, negP, doneS, doneG,
                                               partialS, partialC, out);
}

// Round 6
// 104.016 us; speedup vs baseline: 1.0545x; 1.0545x over previous
//
#include <hip/hip_runtime.h>
#include <stdint.h>

// R5-passing kernel (109.7us, absmax 0.0) + ONE change: XCD-aware block
// swizzle in k_mine. R5 profile showed k_mine = 44.6us (latency-bound:
// ~10x above BW/compute bound; per-XCD gH working set 6MB > 4MB L2 ->
// thrash to MALL). Swizzle gives each XCD exactly 2 subjects (~0.6MB).

#define N 8192
#define D 256
#define NSUBJ 16
#define PADS 768                 // padded slot per subject (mean 512, +11 sigma safe)
#define GN (NSUBJ * PADS)        // 12288 gathered rows
#define MARGIN 1.0f

typedef __attribute__((ext_vector_type(8))) short short8;   // 8 bf16 = 4 VGPRs (MFMA A/B frag)
typedef __attribute__((ext_vector_type(4))) float f32x4;    // MFMA C/D frag
typedef __attribute__((ext_vector_type(4))) unsigned short us4;
typedef unsigned long long u64;

__device__ __forceinline__ unsigned short f2bf(float x) {
    unsigned u = __float_as_uint(x);
    u += 0x7fffu + ((u >> 16) & 1u);
    return (unsigned short)(u >> 16);
}

// ---------------- ws layout ----------------
// ushort gH[GN*D]; u64 posP[GN]; u64 negP[GN]; int gIdx[GN]; int gLab[GN];
// float gSq[GN]; int writePtr[16]; int doneS[16]; int doneG; float partialS[16];
// float partialC[16]; int pos[N]

// R0-proven: init (posP/negP/gIdx/gLab all slots) + within-subject rank scan
// (1 block/subject). Also zeroes doneS/doneG for the k_mine tail cascade.
__global__ void k_prep(const int* __restrict__ sbjv, int* __restrict__ pos,
                       int* __restrict__ writePtr, int* __restrict__ gIdx,
                       int* __restrict__ gLab, u64* __restrict__ posP,
                       u64* __restrict__ negP, int* __restrict__ doneS,
                       int* __restrict__ doneG) {
    int s = blockIdx.x;                 // 0..15
    int tid = threadIdx.x;              // 256
    int lane = tid & 63, w = tid >> 6;

    #pragma unroll
    for (int it = 0; it < 3; ++it) {
        int slot = s * PADS + it * 256 + tid;
        gIdx[slot] = -1;
        gLab[slot] = -2;
        posP[slot] = 0ull;
        negP[slot] = ~0ull;
    }
    if (tid == 0) {
        doneS[s] = 0;
        if (s == 0) *doneG = 0;
    }

    __shared__ int wsum[4];
    __shared__ int carry;
    if (tid == 0) carry = s * PADS;
    __syncthreads();

    for (int iter = 0; iter < 8; ++iter) {          // 1024 rows per iter, int4/thread
        int r0 = iter * 1024 + tid * 4;
        int4 sv = *(const int4*)(sbjv + r0);
        int m0 = (sv.x == s), m1 = (sv.y == s), m2 = (sv.z == s), m3 = (sv.w == s);
        int cnt = m0 + m1 + m2 + m3;
        int x = cnt;                                 // wave inclusive scan
        #pragma unroll
        for (int o = 1; o < 64; o <<= 1) {
            int y = __shfl_up(x, o, 64);
            if (lane >= o) x += y;
        }
        if (lane == 63) wsum[w] = x;
        __syncthreads();                             // A: wsum + carry visible
        int b = carry + (x - cnt);
        #pragma unroll
        for (int ww = 0; ww < 4; ++ww) if (ww < w) b += wsum[ww];
        if (m0) pos[r0 + 0] = b++;
        if (m1) pos[r0 + 1] = b++;
        if (m2) pos[r0 + 2] = b++;
        if (m3) pos[r0 + 3] = b++;
        __syncthreads();                             // B: all reads of carry done
        if (tid == 0) carry += wsum[0] + wsum[1] + wsum[2] + wsum[3];
    }
    __syncthreads();
    if (tid == 0) writePtr[s] = carry;               // == s*PADS + count(s)
}

// R0-proven: gather rows by subject into precomputed slots; fp32 -> bf16;
// fold in sq-norm. posP/negP already initialized by k_prep.
__global__ void k_scatter(const float* __restrict__ emb, const int* __restrict__ labels,
                          const int* __restrict__ sbjv, const int* __restrict__ pos,
                          unsigned short* __restrict__ gH, int* __restrict__ gIdx,
                          int* __restrict__ gLab, float* __restrict__ gSq) {
    int wave = threadIdx.x >> 6;
    int lane = threadIdx.x & 63;
    int row = blockIdx.x * 4 + wave;
    const float4* e4 = (const float4*)(emb + (size_t)row * D);
    float4 v = e4[lane];
    float s = v.x * v.x + v.y * v.y + v.z * v.z + v.w * v.w;
    #pragma unroll
    for (int o = 32; o; o >>= 1) s += __shfl_xor(s, o, 64);
    int p = pos[row];                    // wave-uniform load, no atomics
    us4 h;
    h.x = f2bf(v.x); h.y = f2bf(v.y); h.z = f2bf(v.z); h.w = f2bf(v.w);
    *(us4*)(gH + (size_t)p * D + lane * 4) = h;
    if (lane == 0) { gIdx[p] = row; gLab[p] = labels[row]; gSq[p] = s; }
}

// mining body for one 64x64 tile (one wave). Identical math to the proven
// R0/R2/R5 k_mine (bit-identical packed keys).
__device__ __forceinline__ void mine_tile(
        int s, int rowt, int ctile, int lane,
        const unsigned short* __restrict__ gH, const int* __restrict__ gIdx,
        const int* __restrict__ gLab, const float* __restrict__ gSq,
        const int* __restrict__ writePtr,
        u64* __restrict__ posP, u64* __restrict__ negP) {
    int quad = lane >> 4, l15 = lane & 15;
    int base = s * PADS;
    int cntS = writePtr[s] - base;
    if (rowt * 64 >= cntS || ctile * 64 >= cntS) return;   // wave-uniform exit
    int i0 = base + rowt * 64;
    int j0 = base + ctile * 64;

    int labc[4], idxc[4];
    float sqc[4];
    #pragma unroll
    for (int nt = 0; nt < 4; ++nt) {
        int cidx = j0 + nt * 16 + l15;
        labc[nt] = gLab[cidx]; idxc[nt] = gIdx[cidx]; sqc[nt] = gSq[cidx];
    }
    int labr[4][4], idxr[4][4];
    float sqr[4][4];
    #pragma unroll
    for (int mt = 0; mt < 4; ++mt)
        #pragma unroll
        for (int rg = 0; rg < 4; ++rg) {
            int r = i0 + mt * 16 + quad * 4 + rg;
            labr[mt][rg] = gLab[r]; idxr[mt][rg] = gIdx[r]; sqr[mt][rg] = gSq[r];
        }

    f32x4 acc[4][4];
    #pragma unroll
    for (int mt = 0; mt < 4; ++mt)
        #pragma unroll
        for (int nt = 0; nt < 4; ++nt) {
            f32x4 z = {0.f, 0.f, 0.f, 0.f};
            acc[mt][nt] = z;
        }

    #pragma unroll 2
    for (int kb = 0; kb < 8; ++kb) {
        int koff = kb * 32 + quad * 8;
        short8 a[4], b[4];
        #pragma unroll
        for (int mt = 0; mt < 4; ++mt)
            a[mt] = *(const short8*)(gH + (size_t)(i0 + mt * 16 + l15) * D + koff);
        #pragma unroll
        for (int nt = 0; nt < 4; ++nt)
            b[nt] = *(const short8*)(gH + (size_t)(j0 + nt * 16 + l15) * D + koff);
        #pragma unroll
        for (int mt = 0; mt < 4; ++mt)
            #pragma unroll
            for (int nt = 0; nt < 4; ++nt)
                acc[mt][nt] = __builtin_amdgcn_mfma_f32_16x16x32_bf16(
                    a[mt], b[nt], acc[mt][nt], 0, 0, 0);
    }

    // ---- mining epilogue: C layout col = lane&15, row = quad*4 + reg ----
    #pragma unroll
    for (int mt = 0; mt < 4; ++mt) {
        u64 bp[4], bn[4];
        #pragma unroll
        for (int rg = 0; rg < 4; ++rg) { bp[rg] = 0ull; bn[rg] = ~0ull; }
        #pragma unroll
        for (int nt = 0; nt < 4; ++nt) {
            int lc = labc[nt], ic = idxc[nt];
            float sc = sqc[nt];
            f32x4 v = acc[mt][nt];
            #pragma unroll
            for (int rg = 0; rg < 4; ++rg) {
                float d2 = fmaxf(sqr[mt][rg] + sc - 2.0f * v[rg], 0.0f);
                u64 db = ((u64)__float_as_uint(d2)) << 32;
                if (lc == labr[mt][rg] && ic != idxr[mt][rg] && ic >= 0) {
                    u64 pk = db | (u64)(unsigned)(~(unsigned)ic);
                    if (pk > bp[rg]) bp[rg] = pk;
                }
                if (lc != labr[mt][rg] && ic >= 0) {
                    u64 nk = db | (u64)(unsigned)ic;
                    if (nk < bn[rg]) bn[rg] = nk;
                }
            }
        }
        #pragma unroll
        for (int o = 1; o < 16; o <<= 1) {
            #pragma unroll
            for (int rg = 0; rg < 4; ++rg) {
                u64 pp = __shfl_xor(bp[rg], o, 64);
                if (pp > bp[rg]) bp[rg] = pp;
                u64 qq = __shfl_xor(bn[rg], o, 64);
                if (qq < bn[rg]) bn[rg] = qq;
            }
        }
        if (l15 == 0) {
            #pragma unroll
            for (int rg = 0; rg < 4; ++rg) {
                int r = i0 + mt * 16 + quad * 4 + rg;
                if (bp[rg]) atomicMax(&posP[r], bp[rg]);
                if (bn[rg] != ~0ull) atomicMin(&negP[r], bn[rg]);
            }
        }
    }
}

// R2/R5-proven mining + distributed loss tail, with NEW XCD-aware swizzle:
// 576 blocks = 8 XCDs x 72 tiles. tile = (bid%8)*72 + bid/8 (bijective).
// Consecutive bid round-robin across XCDs (HW heuristic) => XCD x executes
// tiles [72x, 72x+72) = subjects {2x, 2x+1}: per-XCD gH read set ~0.6MB,
// fits 4MB L2 (was 6MB thrash to LLC). Worst case (mapping differs): pure
// permutation, correctness unaffected.
__global__ __launch_bounds__(256) void k_mine(
        const unsigned short* __restrict__ gH, const int* __restrict__ gIdx,
        const int* __restrict__ gLab, const float* __restrict__ gSq,
        const int* __restrict__ writePtr,
        u64* __restrict__ posP, u64* __restrict__ negP,
        int* __restrict__ doneS, int* __restrict__ doneG,
        float* __restrict__ partialS, float* __restrict__ partialC,
        float* __restrict__ out) {
    int bid = blockIdx.x;
    int blk = (bid & 7) * 72 + (bid >> 3);      // XCD-aware tile remap
    int s   = blk / 36;
    int rem = blk % 36;
    int rowt = rem / 3, cgp = rem % 3;
    int tid  = threadIdx.x;
    int lane = tid & 63, w = tid >> 6;
    int ctile = cgp * 4 + w;

    mine_tile(s, rowt, ctile, lane, gH, gIdx, gLab, gSq, writePtr, posP, negP);

    // ---- per-subject completion ----
    __syncthreads();
    __shared__ int role;
    if (tid == 0) {
        __threadfence();                        // release this block's atomics
        role = (atomicAdd(&doneS[s], 1) == 35); // last of 36 subject-s blocks
    }
    __syncthreads();
    if (!role) return;

    // ---- subject-s loss partial (deterministic grouping) ----
    __threadfence();
    int base = s * PADS;
    int cntS = writePtr[s] - base;
    float S = 0.f, C = 0.f;
    #pragma unroll
    for (int k = 0; k < 3; ++k) {
        int local = tid + 256 * k;
        if (local < cntS) {
            u64 p  = __hip_atomic_load(&posP[base + local], __ATOMIC_RELAXED,
                                       __HIP_MEMORY_SCOPE_AGENT);
            u64 nn = __hip_atomic_load(&negP[base + local], __ATOMIC_RELAXED,
                                       __HIP_MEMORY_SCOPE_AGENT);
            if (p != 0ull && nn != ~0ull) {
                float dp = sqrtf(__uint_as_float((unsigned)(p >> 32)));
                float dn = sqrtf(__uint_as_float((unsigned)(nn >> 32)));
                S += fmaxf(dp - dn + MARGIN, 0.0f);
                C += 1.0f;
            }
        }
    }
    #pragma unroll
    for (int o = 32; o; o >>= 1) {
        S += __shfl_xor(S, o, 64);
        C += __shfl_xor(C, o, 64);
    }
    __shared__ float ssS[4], ssC[4];
    if (lane == 0) { ssS[w] = S; ssC[w] = C; }
    __syncthreads();
    if (tid == 0) {
        float PS = ssS[0] + ssS[1] + ssS[2] + ssS[3];
        float PC = ssC[0] + ssC[1] + ssC[2] + ssC[3];
        __hip_atomic_store(&partialS[s], PS, __ATOMIC_RELAXED, __HIP_MEMORY_SCOPE_AGENT);
        __hip_atomic_store(&partialC[s], PC, __ATOMIC_RELAXED, __HIP_MEMORY_SCOPE_AGENT);
        __threadfence();
        if (atomicAdd(doneG, 1) == 15) {        // last subject finisher
            __threadfence();
            float TS = 0.f, TC = 0.f;
            #pragma unroll
            for (int s2 = 0; s2 < NSUBJ; ++s2) {
                TS += __hip_atomic_load(&partialS[s2], __ATOMIC_RELAXED,
                                        __HIP_MEMORY_SCOPE_AGENT);
                TC += __hip_atomic_load(&partialC[s2], __ATOMIC_RELAXED,
                                        __HIP_MEMORY_SCOPE_AGENT);
            }
            out[0] = TS / (TC < 1.0f ? 1.0f : TC);
        }
    }
}

extern "C" void kernel_launch(void* const* d_in, const int* in_sizes, int n_in,
                              void* d_out, int out_size, void* d_ws, size_t ws_size,
                              hipStream_t stream) {
    const float* emb  = (const float*)d_in[0];
    const int* labels = (const int*)d_in[1];
    const int* sbjv   = (const int*)d_in[2];
    float* out = (float*)d_out;

    char* ws = (char*)d_ws;
    unsigned short* gH = (unsigned short*)ws;                 // GN*D*2 = 6291456 B
    u64* posP     = (u64*)(ws + 6291456);                     // GN*8 = 98304
    u64* negP     = (u64*)(ws + 6389760);                     // GN*8 = 98304
    int* gIdx     = (int*)(ws + 6488064);                     // GN*4 = 49152
    int* gLab     = (int*)(ws + 6537216);                     // GN*4
    float* gSq    = (float*)(ws + 6586368);                   // GN*4
    int* writePtr = (int*)(ws + 6635520);                     // 64 B
    int* doneS    = (int*)(ws + 6635584);                     // 64 B
    int* doneG    = (int*)(ws + 6635648);                     // 64 B
    float* partialS = (float*)(ws + 6635712);                 // 64 B
    float* partialC = (float*)(ws + 6635776);                 // 64 B
    int* pos      = (int*)(ws + 6635840);                     // N*4 = 32768

    k_prep<<<NSUBJ, 256, 0, stream>>>(sbjv, pos, writePtr, gIdx, gLab, posP,
                                      negP, doneS, doneG);
    k_scatter<<<N / 4, 256, 0, stream>>>(emb, labels, sbjv, pos, gH, gIdx, gLab, gSq);
    k_mine<<<NSUBJ * 12 * 3, 256, 0, stream>>>(gH, gIdx, gLab, gSq, writePtr,
                                               posP, negP, doneS, doneG,
                                               partialS, partialC, out);
}